// Round 10
// baseline (364.517 us; speedup 1.0000x reference)
//
#include <hip/hip_runtime.h>
#include <hip/hip_bf16.h>
#include <type_traits>

// GNN: GAT(128->4x32) -> GAT(128->4x32) -> GraphConv(128->32) -> SAGE(32->32)
//      -> global mean pool (64 graphs) -> MLP(32->32->10)
// R1: CSR gather aggregation, fp32.                         944 us
// R2: bf16 features + cooperative alpha.                    782 us
// R3: parallel scan + MFMA bf16 GEMMs.                      523 us
// R4: wave-per-dst aggr — FAILED (shfl from exec-inactive lane).
// R5: fixed wave-per-dst single-pass aggr.                  460 us
// R6: no-max softmax, GraphConv linearity reorder.          419 us
// R7: bucketed CSR build (counting sort by dst>>8).         361 us
// R8: branchless aggr + attention dots fused into GEMM.     357 us
// R9: pk-fma + saddr offsets (neutral -> NOT VALU-bound).   361 us
//     (~44 us/iter is harness workspace re-poison — untouchable floor)
// R10: fixed-capacity buckets (drop bucket_hist + memset: 15->12 dispatches),
//      packed int2 rowdeg, mask-free batch-4 gather in gat_aggr (4 loads in
//      flight, zero predicates — s_w zero-padding covers all pad lanes).

typedef __bf16 v8bf __attribute__((ext_vector_type(8)));
typedef float  v4f  __attribute__((ext_vector_type(4)));
typedef float  v2f  __attribute__((ext_vector_type(2)));

#define BCAP 6144   // per-bucket capacity (mean 4096, >20 sigma)

__device__ __forceinline__ float lrelu(float x) { return x > 0.f ? x : 0.2f * x; }

__device__ __forceinline__ unsigned short f2bf(float f) {
    unsigned u = __float_as_uint(f);
    unsigned r = (u + 0x7FFF + ((u >> 16) & 1)) >> 16;   // RNE
    return (unsigned short)r;
}
__device__ __forceinline__ float bfbits2f(unsigned short u) {
    return __uint_as_float((unsigned)u << 16);
}
__device__ __forceinline__ float bflo(int v) { return __uint_as_float((unsigned)v << 16); }
__device__ __forceinline__ float bfhi(int v) { return __uint_as_float((unsigned)v & 0xffff0000u); }
__device__ __forceinline__ v2f up2(int v) {
    v2f r; r.x = bflo(v); r.y = bfhi(v); return r;
}
__device__ __forceinline__ int packbf2(float a, float b) {
    return (int)f2bf(a) | ((int)f2bf(b) << 16);
}

// ================= bucketed CSR build (fixed-capacity buckets) =================
// bucket = dst >> 8; pairs word = (dst&255)<<17 | src; bucket b owns
// pairs[b*BCAP .. gcursor[b]) after scatter.

// block 0: init per-bucket cursors. blocks 1..64: weight prep (transpose+bf16
// and attention-dot columns Vs/Vd in hi+lo bf16 split as rows 128..143).
__global__ __launch_bounds__(256) void prep_kernel(
    int* __restrict__ gcursor,
    const float* __restrict__ W1, const float* __restrict__ W2,
    const float* __restrict__ W3r, const float* __restrict__ W3l,
    const float* __restrict__ as1, const float* __restrict__ ad1,
    const float* __restrict__ as2, const float* __restrict__ ad2,
    __hip_bfloat16* __restrict__ W1t, __hip_bfloat16* __restrict__ W2t,
    __hip_bfloat16* __restrict__ W3rt, __hip_bfloat16* __restrict__ W3lt)
{
    int t = threadIdx.x;
    if (blockIdx.x == 0) {
        gcursor[t] = t * BCAP;
        return;
    }
    int b = blockIdx.x - 1;                 // 0..63
    int i = b * 256 + t;                    // 0..16383
    {   // transpose W1/W2 into rows 0..127 of the 144-row layout
        int k = i >> 7, c = i & 127;
        *(unsigned short*)&W1t[c * 128 + k] = f2bf(W1[i]);
        *(unsigned short*)&W2t[c * 128 + k] = f2bf(W2[i]);
    }
    if (i < 4096) {
        int k = i >> 5, c = i & 31;
        *(unsigned short*)&W3rt[c * 128 + k] = f2bf(W3r[i]);
        *(unsigned short*)&W3lt[c * 128 + k] = f2bf(W3l[i]);
    }
    if (b == 0) {                           // attention-dot columns: 512 units
        for (int u = t; u < 512; u += 256) {
            int k = u & 127, hd = u >> 7;
            float vs1 = 0.f, vd1 = 0.f, vs2 = 0.f, vd2 = 0.f;
            #pragma unroll
            for (int j = 0; j < 32; ++j) {
                int c = hd * 32 + j;
                float w1 = W1[k * 128 + c], w2 = W2[k * 128 + c];
                vs1 += w1 * as1[c]; vd1 += w1 * ad1[c];
                vs2 += w2 * as2[c]; vd2 += w2 * ad2[c];
            }
            unsigned short h1s = f2bf(vs1), h1d = f2bf(vd1);
            unsigned short h2s = f2bf(vs2), h2d = f2bf(vd2);
            *(unsigned short*)&W1t[(128 + hd) * 128 + k] = h1s;
            *(unsigned short*)&W1t[(132 + hd) * 128 + k] = f2bf(vs1 - bfbits2f(h1s));
            *(unsigned short*)&W1t[(136 + hd) * 128 + k] = h1d;
            *(unsigned short*)&W1t[(140 + hd) * 128 + k] = f2bf(vd1 - bfbits2f(h1d));
            *(unsigned short*)&W2t[(128 + hd) * 128 + k] = h2s;
            *(unsigned short*)&W2t[(132 + hd) * 128 + k] = f2bf(vs2 - bfbits2f(h2s));
            *(unsigned short*)&W2t[(136 + hd) * 128 + k] = h2d;
            *(unsigned short*)&W2t[(140 + hd) * 128 + k] = f2bf(vd2 - bfbits2f(h2d));
        }
    }
}

__global__ __launch_bounds__(256) void bucket_scatter(const int* __restrict__ dst,
                                                      const int* __restrict__ src,
                                                      int* __restrict__ gcursor,
                                                      int* __restrict__ pairs,
                                                      int E, int nbuck) {
    __shared__ int hist[256], lcur[256];
    int t = threadIdx.x;
    for (int i = t; i < nbuck; i += 256) hist[i] = 0;
    __syncthreads();
    int base = blockIdx.x * 2048;
    int dreg[8];
    #pragma unroll
    for (int k = 0; k < 8; ++k) {
        int e = base + k * 256 + t;
        int d = (e < E) ? dst[e] : -1;
        dreg[k] = d;
        if (d >= 0) atomicAdd(&hist[d >> 8], 1);
    }
    __syncthreads();
    for (int i = t; i < nbuck; i += 256) {
        int c = hist[i];
        lcur[i] = c ? atomicAdd(&gcursor[i], c) : 0;   // reserve contiguous run
    }
    __syncthreads();
    #pragma unroll
    for (int k = 0; k < 8; ++k) {
        int e = base + k * 256 + t;
        if (e < E) {
            int d = dreg[k];
            int p = atomicAdd(&lcur[d >> 8], 1);
            pairs[p] = ((d & 255) << 17) | src[e];
        }
    }
}

__global__ __launch_bounds__(256) void bucket_fill(const int* __restrict__ pairs,
                                                   const int* __restrict__ gcursor,
                                                   int2* __restrict__ rowdeg,
                                                   int* __restrict__ colsrc, int n) {
    __shared__ int deg[256], excl[256], cur[256];
    int b = blockIdx.x, t = threadIdx.x;
    int e0 = b * BCAP, e1 = gcursor[b];
    int d0 = b << 8;
    deg[t] = 0;
    __syncthreads();
    for (int j = e0 + t; j < e1; j += 256)
        atomicAdd(&deg[pairs[j] >> 17], 1);
    __syncthreads();
    int v = deg[t];
    excl[t] = v;
    __syncthreads();
    for (int off = 1; off < 256; off <<= 1) {
        int u = (t >= off) ? excl[t - off] : 0;
        __syncthreads();
        excl[t] += u;
        __syncthreads();
    }
    int base = e0 + excl[t] - v;                   // exclusive within bucket
    if (d0 + t < n) rowdeg[d0 + t] = make_int2(base, v);
    cur[t] = base;
    __syncthreads();
    for (int j = e0 + t; j < e1; j += 256) {
        int w = pairs[j];
        int p = atomicAdd(&cur[w >> 17], 1);
        colsrc[p] = w & 0x1FFFF;
    }
}

// ---------------- GAT GEMM via MFMA: [h | a_s | a_d] = X @ Wt(144 cols) ----------
template <typename T>
__global__ __launch_bounds__(256) void gemm_att_mfma(
    const T* __restrict__ X, const __hip_bfloat16* __restrict__ Wt,
    __hip_bfloat16* __restrict__ h, float* __restrict__ a_s, float* __restrict__ a_d, int n)
{
    __shared__ __align__(16) __hip_bfloat16 sWt[144 * 136];   // [col][k], +8 pad
    int t = threadIdx.x;
    for (int i = t; i < 144 * 16; i += 256) {
        int row = i >> 4, ch = i & 15;
        *(int4*)&sWt[row * 136 + ch * 8] = *(const int4*)&Wt[row * 128 + ch * 8];
    }
    __syncthreads();
    int wave = t >> 6, lane = t & 63, quad = lane >> 4, l16 = lane & 15;
    int rowbase = (blockIdx.x * 4 + wave) * 16;
    if (rowbase >= n) return;

    v8bf z;
    #pragma unroll
    for (int i = 0; i < 8; ++i) z[i] = (__bf16)0.f;
    int arow = rowbase + l16;
    bool ok = arow < n;
    v8bf af[4];
    if constexpr (std::is_same<T, float>::value) {
        const float* xf = X + (size_t)(ok ? arow : 0) * 128;
        #pragma unroll
        for (int ks = 0; ks < 4; ++ks) {
            if (ok) {
                float4 u = *(const float4*)&xf[ks * 32 + quad * 8];
                float4 v = *(const float4*)&xf[ks * 32 + quad * 8 + 4];
                v8bf a;
                unsigned short r;
                r = f2bf(u.x); a[0] = *(__bf16*)&r;
                r = f2bf(u.y); a[1] = *(__bf16*)&r;
                r = f2bf(u.z); a[2] = *(__bf16*)&r;
                r = f2bf(u.w); a[3] = *(__bf16*)&r;
                r = f2bf(v.x); a[4] = *(__bf16*)&r;
                r = f2bf(v.y); a[5] = *(__bf16*)&r;
                r = f2bf(v.z); a[6] = *(__bf16*)&r;
                r = f2bf(v.w); a[7] = *(__bf16*)&r;
                af[ks] = a;
            } else af[ks] = z;
        }
    } else {
        const v8bf* px = (const v8bf*)(X + (size_t)(ok ? arow : 0) * 128);
        #pragma unroll
        for (int ks = 0; ks < 4; ++ks) af[ks] = ok ? px[ks * 4 + quad] : z;
    }

    v4f acc[9];
    #pragma unroll
    for (int ct = 0; ct < 9; ++ct) acc[ct] = (v4f){0.f, 0.f, 0.f, 0.f};
    #pragma unroll
    for (int ct = 0; ct < 9; ++ct) {
        #pragma unroll
        for (int ks = 0; ks < 4; ++ks) {
            v8bf b = *(const v8bf*)&sWt[(ct * 16 + l16) * 136 + ks * 32 + quad * 8];
            acc[ct] = __builtin_amdgcn_mfma_f32_16x16x32_bf16(af[ks], b, acc[ct], 0, 0, 0);
        }
    }

    // h store (tiles 0..7): C layout col=l16, row=quad*4+reg
    #pragma unroll
    for (int reg = 0; reg < 4; ++reg) {
        int r = rowbase + quad * 4 + reg;
        if (r < n) {
            #pragma unroll
            for (int ct = 0; ct < 8; ++ct)
                *(unsigned short*)&h[(size_t)r * 128 + ct * 16 + l16] = f2bf(acc[ct][reg]);
        }
    }
    // tile 8 = attention dots: cols l16: 0-3 s_hi, 4-7 s_lo, 8-11 d_hi, 12-15 d_lo
    #pragma unroll
    for (int reg = 0; reg < 4; ++reg) {
        float v = acc[8][reg] + __shfl_xor(acc[8][reg], 4);   // hi + lo
        int r = rowbase + quad * 4 + reg;
        if (r < n) {
            if (l16 < 4)                    a_s[r * 4 + l16] = v;
            else if (l16 >= 8 && l16 < 12)  a_d[r * 4 + (l16 - 8)] = v;
        }
    }
}

// ---------------- GAT: wave-per-dst aggregation, batch-4 mask-free gather ---------
__global__ __launch_bounds__(256) void gat_aggr(
    const __hip_bfloat16* __restrict__ h, const float* __restrict__ a_s,
    const float* __restrict__ a_d,
    const int2* __restrict__ rowdeg, const int* __restrict__ colsrc,
    const float* __restrict__ bias, __hip_bfloat16* __restrict__ out, int n)
{
    __shared__ float s_w[4][64 * 4];
    int t = threadIdx.x;
    int wave = t >> 6, lane = t & 63;
    int d = blockIdx.x * 4 + wave;
    if (d >= n) d = n - 1;                         // duplicate work, benign
    int2 rd = rowdeg[d];
    int beg = rd.x, cnt = rd.y;
    float4 ad4 = *(const float4*)&a_d[d * 4];
    float4 asd = *(const float4*)&a_s[d * 4];
    float es0 = lrelu(asd.x + ad4.x), es1 = lrelu(asd.y + ad4.y);
    float es2 = lrelu(asd.z + ad4.z), es3 = lrelu(asd.w + ad4.w);
    float z0 = 0.f, z1 = 0.f, z2 = 0.f, z3 = 0.f;   // per-lane partials

    int l16 = lane & 15, egrp = lane >> 4;
    unsigned ch2 = (unsigned)(l16 * 16);            // byte offset of channels
    int head = l16 >> 2;
    v2f a2[4];
    #pragma unroll
    for (int i = 0; i < 4; ++i) a2[i] = (v2f){0.f, 0.f};

    for (int j0 = 0; j0 < cnt; j0 += 64) {
        int ne = min(64, cnt - j0);
        float w0 = 0.f, w1 = 0.f, w2 = 0.f, w3 = 0.f;
        int s = 0;                                  // row 0 is a valid address
        if (lane < ne) {
            s = colsrc[beg + j0 + lane];
            float4 sv = *(const float4*)&a_s[s * 4];
            w0 = __expf(lrelu(sv.x + ad4.x));
            w1 = __expf(lrelu(sv.y + ad4.y));
            w2 = __expf(lrelu(sv.z + ad4.z));
            w3 = __expf(lrelu(sv.w + ad4.w));
        }
        z0 += w0; z1 += w1; z2 += w2; z3 += w3;
        float4 wv = {w0, w1, w2, w3};               // zeros for pad lanes
        *(float4*)&s_w[wave][lane * 4] = wv;
        __asm volatile("s_waitcnt lgkmcnt(0)" ::: "memory");  // wave-sync LDS
        // Mask-free: j = egrp+4k <= 4*kmax-1 <= 63 always, and s_w[j]==0 with
        // s==0 (valid row) for pad lanes -> pad iterations contribute exactly 0.
        int kmax = (ne + 3) >> 2;
        int k0 = 0;
        for (; k0 + 4 <= kmax; k0 += 4) {           // full batch: 4 loads in flight
            int ssq[4]; float wq[4];
            #pragma unroll
            for (int q = 0; q < 4; ++q) {
                int j = egrp + 4 * (k0 + q);
                ssq[q] = __shfl(s, j);
                wq[q] = s_w[wave][j * 4 + head];
            }
            int4 uq[4];
            #pragma unroll
            for (int q = 0; q < 4; ++q) {
                unsigned off = ((unsigned)ssq[q] << 8) + ch2;
                uq[q] = *(const int4*)((const char*)h + off);
            }
            #pragma unroll
            for (int q = 0; q < 4; ++q) {
                v2f w2v = {wq[q], wq[q]};
                a2[0] += w2v * up2(uq[q].x);
                a2[1] += w2v * up2(uq[q].y);
                a2[2] += w2v * up2(uq[q].z);
                a2[3] += w2v * up2(uq[q].w);
            }
        }
        for (; k0 < kmax; ++k0) {                   // unpredicated tail
            int j = egrp + 4 * k0;
            int ss = __shfl(s, j);
            float wj = s_w[wave][j * 4 + head];
            v2f w2v = {wj, wj};
            unsigned off = ((unsigned)ss << 8) + ch2;
            int4 u = *(const int4*)((const char*)h + off);
            a2[0] += w2v * up2(u.x);
            a2[1] += w2v * up2(u.y);
            a2[2] += w2v * up2(u.z);
            a2[3] += w2v * up2(u.w);
        }
    }
    float acc[8] = {a2[0].x, a2[0].y, a2[1].x, a2[1].y,
                    a2[2].x, a2[2].y, a2[3].x, a2[3].y};
    #pragma unroll
    for (int off = 1; off < 64; off <<= 1) {
        z0 += __shfl_xor(z0, off);
        z1 += __shfl_xor(z1, off);
        z2 += __shfl_xor(z2, off);
        z3 += __shfl_xor(z3, off);
    }
    #pragma unroll
    for (int off = 16; off < 64; off <<= 1)
        #pragma unroll
        for (int i = 0; i < 8; ++i) acc[i] += __shfl_xor(acc[i], off);

    if (egrp == 0) {                                // lanes 0..15 write 16B each
        int ch = l16 * 8;
        float zh = (head < 2) ? (head == 0 ? z0 : z1) : (head == 2 ? z2 : z3);
        float eh = (head < 2) ? (head == 0 ? es0 : es1) : (head == 2 ? es2 : es3);
        float ws = __expf(eh);                      // self-loop weight
        float inv = 1.f / (zh + ws + 1e-16f);
        int4 hu = *(const int4*)&h[(size_t)d * 128 + ch];
        float hs[8] = {bflo(hu.x), bfhi(hu.x), bflo(hu.y), bfhi(hu.y),
                       bflo(hu.z), bfhi(hu.z), bflo(hu.w), bfhi(hu.w)};
        float4 b0 = *(const float4*)&bias[ch];
        float4 b1 = *(const float4*)&bias[ch + 4];
        float o[8];
        o[0] = fmaxf((acc[0] + ws * hs[0]) * inv + b0.x, 0.f);
        o[1] = fmaxf((acc[1] + ws * hs[1]) * inv + b0.y, 0.f);
        o[2] = fmaxf((acc[2] + ws * hs[2]) * inv + b0.z, 0.f);
        o[3] = fmaxf((acc[3] + ws * hs[3]) * inv + b0.w, 0.f);
        o[4] = fmaxf((acc[4] + ws * hs[4]) * inv + b1.x, 0.f);
        o[5] = fmaxf((acc[5] + ws * hs[5]) * inv + b1.y, 0.f);
        o[6] = fmaxf((acc[6] + ws * hs[6]) * inv + b1.z, 0.f);
        o[7] = fmaxf((acc[7] + ws * hs[7]) * inv + b1.w, 0.f);
        int4 ou;
        ou.x = packbf2(o[0], o[1]); ou.y = packbf2(o[2], o[3]);
        ou.z = packbf2(o[4], o[5]); ou.w = packbf2(o[6], o[7]);
        *(int4*)&out[(size_t)d * 128 + ch] = ou;
    }
}

// ---------------- GraphConv linear: y = x@Wr (bf16), root = x@Wl + b (fp32) -------
__global__ __launch_bounds__(256) void graphconv_lin(
    const __hip_bfloat16* __restrict__ Xb,
    const __hip_bfloat16* __restrict__ Wrt, const __hip_bfloat16* __restrict__ Wlt,
    const float* __restrict__ bias, __hip_bfloat16* __restrict__ y,
    float* __restrict__ root, int n)
{
    __shared__ __align__(16) __hip_bfloat16 sWr[32 * 136], sWl[32 * 136];
    int t = threadIdx.x;
    for (int i = t; i < 32 * 16; i += 256) {
        int row = i >> 4, ch = i & 15;
        *(int4*)&sWr[row * 136 + ch * 8] = *(const int4*)&Wrt[row * 128 + ch * 8];
        *(int4*)&sWl[row * 136 + ch * 8] = *(const int4*)&Wlt[row * 128 + ch * 8];
    }
    __syncthreads();
    int wave = t >> 6, lane = t & 63, quad = lane >> 4, l16 = lane & 15;
    int rowbase = (blockIdx.x * 4 + wave) * 16;
    if (rowbase >= n) return;

    v8bf z;
    #pragma unroll
    for (int i = 0; i < 8; ++i) z[i] = (__bf16)0.f;
    int arow = rowbase + l16;
    bool ok = arow < n;
    const v8bf* px = (const v8bf*)(Xb + (size_t)(ok ? arow : 0) * 128);
    v8bf fx[4];
    #pragma unroll
    for (int ks = 0; ks < 4; ++ks) fx[ks] = ok ? px[ks * 4 + quad] : z;

    v4f accR[2], accL[2];
    #pragma unroll
    for (int ct = 0; ct < 2; ++ct) {
        accR[ct] = (v4f){0.f, 0.f, 0.f, 0.f};
        accL[ct] = (v4f){0.f, 0.f, 0.f, 0.f};
        #pragma unroll
        for (int ks = 0; ks < 4; ++ks) {
            v8bf br = *(const v8bf*)&sWr[(ct * 16 + l16) * 136 + ks * 32 + quad * 8];
            accR[ct] = __builtin_amdgcn_mfma_f32_16x16x32_bf16(fx[ks], br, accR[ct], 0, 0, 0);
            v8bf bl = *(const v8bf*)&sWl[(ct * 16 + l16) * 136 + ks * 32 + quad * 8];
            accL[ct] = __builtin_amdgcn_mfma_f32_16x16x32_bf16(fx[ks], bl, accL[ct], 0, 0, 0);
        }
    }
    #pragma unroll
    for (int ct = 0; ct < 2; ++ct) {
        float bcol = bias[ct * 16 + l16];
        #pragma unroll
        for (int reg = 0; reg < 4; ++reg) {
            int r = rowbase + quad * 4 + reg;
            if (r < n) {
                *(unsigned short*)&y[(size_t)r * 32 + ct * 16 + l16] = f2bf(accR[ct][reg]);
                root[(size_t)r * 32 + ct * 16 + l16] = accL[ct][reg] + bcol;
            }
        }
    }
}

// ---------------- GraphConv aggr: x3 = relu(sum_{src} y[src] + root), 32 ch -------
__global__ __launch_bounds__(256) void graphconv_aggr(
    const __hip_bfloat16* __restrict__ y, const float* __restrict__ root,
    const int2* __restrict__ rowdeg, const int* __restrict__ colsrc,
    __hip_bfloat16* __restrict__ x3, int n)
{
    int t = threadIdx.x;
    int wave = t >> 6, lane = t & 63;
    int d = blockIdx.x * 4 + wave;
    if (d >= n) d = n - 1;
    int2 rd = rowdeg[d];
    int beg = rd.x, cnt = rd.y;
    int l4 = lane & 3, egrp = lane >> 2;      // 16 edges concurrent, 4 lanes/row
    unsigned ch2 = (unsigned)(l4 * 16);
    v2f a2[4];
    #pragma unroll
    for (int i = 0; i < 4; ++i) a2[i] = (v2f){0.f, 0.f};
    for (int j0 = 0; j0 < cnt; j0 += 64) {
        int ne = min(64, cnt - j0);
        int s = (lane < ne) ? colsrc[beg + j0 + lane] : 0;
        int kmax = (ne + 15) >> 4;                  // uniform trip count
        #pragma unroll 2
        for (int k = 0; k < kmax; ++k) {
            int j = egrp + 16 * k;                  // <= 63 always
            int ss = __shfl(s, j);
            float m = (j < ne) ? 1.f : 0.f;         // branchless mask
            v2f m2 = {m, m};
            unsigned off = ((unsigned)ss << 6) + ch2;
            int4 u = *(const int4*)((const char*)y + off);
            a2[0] += m2 * up2(u.x);
            a2[1] += m2 * up2(u.y);
            a2[2] += m2 * up2(u.z);
            a2[3] += m2 * up2(u.w);
        }
    }
    float acc[8] = {a2[0].x, a2[0].y, a2[1].x, a2[1].y,
                    a2[2].x, a2[2].y, a2[3].x, a2[3].y};
    #pragma unroll
    for (int off = 4; off < 64; off <<= 1)
        #pragma unroll
        for (int i = 0; i < 8; ++i) acc[i] += __shfl_xor(acc[i], off);
    if (egrp == 0) {                           // lanes 0..3 write 16B each
        int ch = l4 * 8;
        float4 r0 = *(const float4*)&root[(size_t)d * 32 + ch];
        float4 r1 = *(const float4*)&root[(size_t)d * 32 + ch + 4];
        float o[8];
        o[0] = fmaxf(acc[0] + r0.x, 0.f); o[1] = fmaxf(acc[1] + r0.y, 0.f);
        o[2] = fmaxf(acc[2] + r0.z, 0.f); o[3] = fmaxf(acc[3] + r0.w, 0.f);
        o[4] = fmaxf(acc[4] + r1.x, 0.f); o[5] = fmaxf(acc[5] + r1.y, 0.f);
        o[6] = fmaxf(acc[6] + r1.z, 0.f); o[7] = fmaxf(acc[7] + r1.w, 0.f);
        int4 ou;
        ou.x = packbf2(o[0], o[1]); ou.y = packbf2(o[2], o[3]);
        ou.z = packbf2(o[4], o[5]); ou.w = packbf2(o[6], o[7]);
        *(int4*)&x3[(size_t)d * 32 + ch] = ou;
    }
}

// ---------------- SAGE fused: mean gather + out = relu(mean@Wl+bl + x3@Wr) --------
__global__ __launch_bounds__(256) void sage_fused(
    const __hip_bfloat16* __restrict__ x3, const int2* __restrict__ rowdeg,
    const int* __restrict__ colsrc,
    const float* __restrict__ W4l, const float* __restrict__ b4l,
    const float* __restrict__ W4r, float* __restrict__ out, int n)
{
    __shared__ __align__(16) float sWl[32 * 32], sWr[32 * 32];
    __shared__ float s_mean[4][32], s_x3[4][32];
    int t = threadIdx.x;
    for (int i = t; i < 1024; i += 256) { sWl[i] = W4l[i]; sWr[i] = W4r[i]; }
    __syncthreads();

    int wave = t >> 6, lane = t & 63;
    int d = blockIdx.x * 4 + wave;
    if (d >= n) d = n - 1;
    int2 rd = rowdeg[d];
    int beg = rd.x, cnt = rd.y;
    int l4 = lane & 3, egrp = lane >> 2;
    unsigned ch2 = (unsigned)(l4 * 16);
    v2f a2[4];
    #pragma unroll
    for (int i = 0; i < 4; ++i) a2[i] = (v2f){0.f, 0.f};
    for (int j0 = 0; j0 < cnt; j0 += 64) {
        int ne = min(64, cnt - j0);
        int s = (lane < ne) ? colsrc[beg + j0 + lane] : 0;
        int kmax = (ne + 15) >> 4;
        #pragma unroll 2
        for (int k = 0; k < kmax; ++k) {
            int j = egrp + 16 * k;
            int ss = __shfl(s, j);
            float m = (j < ne) ? 1.f : 0.f;
            v2f m2 = {m, m};
            unsigned off = ((unsigned)ss << 6) + ch2;
            int4 u = *(const int4*)((const char*)x3 + off);
            a2[0] += m2 * up2(u.x);
            a2[1] += m2 * up2(u.y);
            a2[2] += m2 * up2(u.z);
            a2[3] += m2 * up2(u.w);
        }
    }
    float acc[8] = {a2[0].x, a2[0].y, a2[1].x, a2[1].y,
                    a2[2].x, a2[2].y, a2[3].x, a2[3].y};
    #pragma unroll
    for (int off = 4; off < 64; off <<= 1)
        #pragma unroll
        for (int i = 0; i < 8; ++i) acc[i] += __shfl_xor(acc[i], off);
    if (egrp == 0) {                           // lanes 0..3: mean + self row to LDS
        int ch = l4 * 8;
        float invd = 1.f / fmaxf((float)cnt, 1.f);
        int4 xr = *(const int4*)&x3[(size_t)d * 32 + ch];
        #pragma unroll
        for (int i = 0; i < 8; ++i) s_mean[wave][ch + i] = acc[i] * invd;
        s_x3[wave][ch + 0] = bflo(xr.x); s_x3[wave][ch + 1] = bfhi(xr.x);
        s_x3[wave][ch + 2] = bflo(xr.y); s_x3[wave][ch + 3] = bfhi(xr.y);
        s_x3[wave][ch + 4] = bflo(xr.z); s_x3[wave][ch + 5] = bfhi(xr.z);
        s_x3[wave][ch + 6] = bflo(xr.w); s_x3[wave][ch + 7] = bfhi(xr.w);
    }
    __asm volatile("s_waitcnt lgkmcnt(0)" ::: "memory");  // wave-sync LDS
    // matvec: c = lane&31, half = lane>>5 covers k-range half*16..+16
    int c = lane & 31, half = lane >> 5;
    const float* sm = &s_mean[wave][half * 16];
    const float* sx = &s_x3[wave][half * 16];
    float acc2 = 0.f;
    #pragma unroll
    for (int k = 0; k < 16; ++k) {
        int kk = half * 16 + k;
        acc2 += sm[k] * sWl[kk * 32 + c] + sx[k] * sWr[kk * 32 + c];
    }
    acc2 += __shfl_xor(acc2, 32);
    if (half == 0 && d < n)
        out[(size_t)d * 32 + c] = fmaxf(acc2 + b4l[c], 0.f);
}

// ---------------- global mean pool (batch sorted) ----------------
__device__ __forceinline__ int lower_bound_i(const int* a, int n, int key) {
    int lo = 0, hi = n;
    while (lo < hi) { int mid = (lo + hi) >> 1; if (a[mid] < key) lo = mid + 1; else hi = mid; }
    return lo;
}

__global__ __launch_bounds__(256) void pool_kernel(
    const float* __restrict__ x, const int* __restrict__ batch,
    float* __restrict__ gpool, int n)
{
    int g = blockIdx.x;
    int lo = lower_bound_i(batch, n, g);
    int hi = lower_bound_i(batch, n, g + 1);
    int t = threadIdx.x;
    int c = t & 31, rr = t >> 5;
    float acc = 0.f;
    for (int i = lo + rr; i < hi; i += 8) acc += x[i * 32 + c];
    __shared__ float sred[256];
    sred[t] = acc;
    __syncthreads();
    if (t < 128) sred[t] += sred[t + 128];
    __syncthreads();
    if (t < 64) sred[t] += sred[t + 64];
    __syncthreads();
    if (t < 32) {
        float v = sred[t] + sred[t + 32];
        gpool[g * 32 + t] = v / fmaxf((float)(hi - lo), 1.f);
    }
}

// ---------------- MLP head ----------------
__global__ __launch_bounds__(256) void head_kernel(
    const float* __restrict__ gpool, const float* __restrict__ Wf1, const float* __restrict__ bf1,
    const float* __restrict__ Wf2, const float* __restrict__ bf2, float* __restrict__ out)
{
    __shared__ float sg[64 * 32], st[64 * 32];
    __shared__ float sW1[32 * 32], sW2[32 * 10];
    int t = threadIdx.x;
    for (int i = t; i < 2048; i += 256) sg[i] = gpool[i];
    for (int i = t; i < 1024; i += 256) sW1[i] = Wf1[i];
    for (int i = t; i < 320; i += 256) sW2[i] = Wf2[i];
    __syncthreads();
    for (int i = t; i < 2048; i += 256) {
        int g = i >> 5, c = i & 31;
        float acc = bf1[c];
        #pragma unroll
        for (int k = 0; k < 32; ++k) acc += sg[g * 32 + k] * sW1[k * 32 + c];
        st[i] = fmaxf(acc, 0.f);
    }
    __syncthreads();
    for (int i = t; i < 640; i += 256) {
        int g = i / 10, o = i - g * 10;
        float acc = bf2[o];
        #pragma unroll
        for (int k = 0; k < 32; ++k) acc += st[g * 32 + k] * sW2[k * 10 + o];
        out[i] = acc;
    }
}

extern "C" void kernel_launch(void* const* d_in, const int* in_sizes, int n_in,
                              void* d_out, int out_size, void* d_ws, size_t ws_size,
                              hipStream_t stream) {
    const float* x    = (const float*)d_in[0];
    const int*   ei   = (const int*)d_in[1];
    const int*   batch= (const int*)d_in[2];
    const float* W1   = (const float*)d_in[3];
    const float* as1  = (const float*)d_in[4];
    const float* ad1  = (const float*)d_in[5];
    const float* b1   = (const float*)d_in[6];
    const float* W2   = (const float*)d_in[7];
    const float* as2  = (const float*)d_in[8];
    const float* ad2  = (const float*)d_in[9];
    const float* b2   = (const float*)d_in[10];
    const float* W3r  = (const float*)d_in[11];
    const float* W3l  = (const float*)d_in[12];
    const float* b3   = (const float*)d_in[13];
    const float* W4l  = (const float*)d_in[14];
    const float* b4l  = (const float*)d_in[15];
    const float* W4r  = (const float*)d_in[16];
    const float* Wf1  = (const float*)d_in[17];
    const float* bf1  = (const float*)d_in[18];
    const float* Wf2  = (const float*)d_in[19];
    const float* bf2  = (const float*)d_in[20];

    const int N = in_sizes[0] / 128;
    const int E = in_sizes[1] / 2;
    const int* src = ei;
    const int* dst = ei + E;

    char* p = (char*)d_ws;
    auto alloc = [&](size_t bytes) -> void* {
        void* r = (void*)p;
        p += (bytes + 255) & ~(size_t)255;
        return r;
    };
    const int nbuck = (N + 255) >> 8;     // 196 for N=50000 (requires N<=65536)

    __hip_bfloat16* buf1 = (__hip_bfloat16*)alloc((size_t)N * 128 * 2);  // x2 / X4
    __hip_bfloat16* buf2 = (__hip_bfloat16*)alloc((size_t)N * 128 * 2);  // x1 / x3
    __hip_bfloat16* buf3 = (__hip_bfloat16*)alloc((size_t)N * 128 * 2);  // pairs / h1,h2 / y+root
    float* aS     = (float*)alloc((size_t)N * 4 * 4);
    float* aD     = (float*)alloc((size_t)N * 4 * 4);
    int2*  rowdeg = (int2*)alloc((size_t)N * 8);
    int*   colsrc = (int*)alloc((size_t)nbuck * BCAP * 4);
    int*   gcursor= (int*)alloc(256 * 4);
    __hip_bfloat16* W1t  = (__hip_bfloat16*)alloc(144 * 128 * 2);
    __hip_bfloat16* W2t  = (__hip_bfloat16*)alloc(144 * 128 * 2);
    __hip_bfloat16* W3rt = (__hip_bfloat16*)alloc(32 * 128 * 2);
    __hip_bfloat16* W3lt = (__hip_bfloat16*)alloc(32 * 128 * 2);
    float* gpool  = (float*)alloc(64 * 32 * 4);

    // aliased views
    __hip_bfloat16* X3b  = buf2;                                        // N*32 bf16
    float*          X4   = (float*)buf1;                                // N*32 fp32
    __hip_bfloat16* Y32  = buf3;                                        // N*32 bf16
    float*          ROOT = (float*)((char*)buf3 + (((size_t)N * 32 * 2 + 255) & ~(size_t)255));
    int*            pairs = (int*)buf3;   // nbuck*BCAP*4 B <= 4.8 MB, consumed before h

    // ---- CSR build (fixed-capacity buckets) + weight prep: 3 dispatches ----
    prep_kernel<<<65, 256, 0, stream>>>(gcursor, W1, W2, W3r, W3l,
                                        as1, ad1, as2, ad2, W1t, W2t, W3rt, W3lt);
    bucket_scatter<<<(E + 2047) / 2048, 256, 0, stream>>>(dst, src, gcursor, pairs, E, nbuck);
    bucket_fill<<<nbuck, 256, 0, stream>>>(pairs, gcursor, rowdeg, colsrc, N);

    const int gmm = (N + 63) / 64;
    const int gag = (N + 3) / 4;
    // GAT layer 1 (reads fp32 x directly)
    gemm_att_mfma<float><<<gmm, 256, 0, stream>>>(x, W1t, buf3, aS, aD, N);
    gat_aggr<<<gag, 256, 0, stream>>>(buf3, aS, aD, rowdeg, colsrc, b1, buf2, N);
    // GAT layer 2
    gemm_att_mfma<__hip_bfloat16><<<gmm, 256, 0, stream>>>(buf2, W2t, buf3, aS, aD, N);
    gat_aggr<<<gag, 256, 0, stream>>>(buf3, aS, aD, rowdeg, colsrc, b2, buf1, N);
    // GraphConv (project first, then 64B-row gather)
    graphconv_lin<<<gmm, 256, 0, stream>>>(buf1, W3rt, W3lt, b3, Y32, ROOT, N);
    graphconv_aggr<<<gag, 256, 0, stream>>>(Y32, ROOT, rowdeg, colsrc, X3b, N);
    // SAGE (mean gather + GEMM fused; MEAN never materialized)
    sage_fused<<<gag, 256, 0, stream>>>(X3b, rowdeg, colsrc, W4l, b4l, W4r, X4, N);
    // pool + head
    pool_kernel<<<64, 256, 0, stream>>>(X4, batch, gpool, N);
    head_kernel<<<1, 256, 0, stream>>>(gpool, Wf1, bf1, Wf2, bf2, (float*)d_out);
}

// Round 11
// 358.616 us; speedup vs baseline: 1.0165x; 1.0165x over previous
//
#include <hip/hip_runtime.h>
#include <hip/hip_bf16.h>
#include <type_traits>

// GNN: GAT(128->4x32) -> GAT(128->4x32) -> GraphConv(128->32) -> SAGE(32->32)
//      -> global mean pool (64 graphs) -> MLP(32->32->10)
// R1: CSR gather aggregation, fp32.                         944 us
// R2: bf16 features + cooperative alpha.                    782 us
// R3: parallel scan + MFMA bf16 GEMMs.                      523 us
// R4: wave-per-dst aggr — FAILED (shfl from exec-inactive lane).
// R5: fixed wave-per-dst single-pass aggr.                  460 us
// R6: no-max softmax, GraphConv linearity reorder.          419 us
// R7: bucketed CSR build (counting sort by dst>>8).         361 us
// R8: branchless aggr + attention dots fused into GEMM.     357 us
// R9: pk-fma + saddr offsets (neutral -> NOT VALU-bound).   361 us
// R10: 3-dispatch CSR build (kept) + batch-4 gather — REGRESSED:
//      VGPR 28->44, occupancy 68->42%, gat_aggr 43.8->47.9 us. ILP<TLP
//      on a latency-bound gather.                           364 us
// R11: revert gat_aggr inner loop to the 28-VGPR unroll-2 form; keep
//      fixed-capacity CSR build + int2 rowdeg.
//      (~44 us/iter is harness workspace re-poison — untouchable floor;
//       gat_aggr ~43.5 us = 94 MB random 256B gathers @ ~2.5 TB/s,
//       occupancy-bound, micro-opt-insensitive.)

typedef __bf16 v8bf __attribute__((ext_vector_type(8)));
typedef float  v4f  __attribute__((ext_vector_type(4)));
typedef float  v2f  __attribute__((ext_vector_type(2)));

#define BCAP 6144   // per-bucket capacity (mean 4096, >20 sigma)

__device__ __forceinline__ float lrelu(float x) { return x > 0.f ? x : 0.2f * x; }

__device__ __forceinline__ unsigned short f2bf(float f) {
    unsigned u = __float_as_uint(f);
    unsigned r = (u + 0x7FFF + ((u >> 16) & 1)) >> 16;   // RNE
    return (unsigned short)r;
}
__device__ __forceinline__ float bfbits2f(unsigned short u) {
    return __uint_as_float((unsigned)u << 16);
}
__device__ __forceinline__ float bflo(int v) { return __uint_as_float((unsigned)v << 16); }
__device__ __forceinline__ float bfhi(int v) { return __uint_as_float((unsigned)v & 0xffff0000u); }
__device__ __forceinline__ v2f up2(int v) {
    v2f r; r.x = bflo(v); r.y = bfhi(v); return r;
}
__device__ __forceinline__ int packbf2(float a, float b) {
    return (int)f2bf(a) | ((int)f2bf(b) << 16);
}

// ================= bucketed CSR build (fixed-capacity buckets) =================
// bucket = dst >> 8; pairs word = (dst&255)<<17 | src; bucket b owns
// pairs[b*BCAP .. gcursor[b]) after scatter.

// block 0: init per-bucket cursors. blocks 1..64: weight prep (transpose+bf16
// and attention-dot columns Vs/Vd in hi+lo bf16 split as rows 128..143).
__global__ __launch_bounds__(256) void prep_kernel(
    int* __restrict__ gcursor,
    const float* __restrict__ W1, const float* __restrict__ W2,
    const float* __restrict__ W3r, const float* __restrict__ W3l,
    const float* __restrict__ as1, const float* __restrict__ ad1,
    const float* __restrict__ as2, const float* __restrict__ ad2,
    __hip_bfloat16* __restrict__ W1t, __hip_bfloat16* __restrict__ W2t,
    __hip_bfloat16* __restrict__ W3rt, __hip_bfloat16* __restrict__ W3lt)
{
    int t = threadIdx.x;
    if (blockIdx.x == 0) {
        gcursor[t] = t * BCAP;
        return;
    }
    int b = blockIdx.x - 1;                 // 0..63
    int i = b * 256 + t;                    // 0..16383
    {   // transpose W1/W2 into rows 0..127 of the 144-row layout
        int k = i >> 7, c = i & 127;
        *(unsigned short*)&W1t[c * 128 + k] = f2bf(W1[i]);
        *(unsigned short*)&W2t[c * 128 + k] = f2bf(W2[i]);
    }
    if (i < 4096) {
        int k = i >> 5, c = i & 31;
        *(unsigned short*)&W3rt[c * 128 + k] = f2bf(W3r[i]);
        *(unsigned short*)&W3lt[c * 128 + k] = f2bf(W3l[i]);
    }
    if (b == 0) {                           // attention-dot columns: 512 units
        for (int u = t; u < 512; u += 256) {
            int k = u & 127, hd = u >> 7;
            float vs1 = 0.f, vd1 = 0.f, vs2 = 0.f, vd2 = 0.f;
            #pragma unroll
            for (int j = 0; j < 32; ++j) {
                int c = hd * 32 + j;
                float w1 = W1[k * 128 + c], w2 = W2[k * 128 + c];
                vs1 += w1 * as1[c]; vd1 += w1 * ad1[c];
                vs2 += w2 * as2[c]; vd2 += w2 * ad2[c];
            }
            unsigned short h1s = f2bf(vs1), h1d = f2bf(vd1);
            unsigned short h2s = f2bf(vs2), h2d = f2bf(vd2);
            *(unsigned short*)&W1t[(128 + hd) * 128 + k] = h1s;
            *(unsigned short*)&W1t[(132 + hd) * 128 + k] = f2bf(vs1 - bfbits2f(h1s));
            *(unsigned short*)&W1t[(136 + hd) * 128 + k] = h1d;
            *(unsigned short*)&W1t[(140 + hd) * 128 + k] = f2bf(vd1 - bfbits2f(h1d));
            *(unsigned short*)&W2t[(128 + hd) * 128 + k] = h2s;
            *(unsigned short*)&W2t[(132 + hd) * 128 + k] = f2bf(vs2 - bfbits2f(h2s));
            *(unsigned short*)&W2t[(136 + hd) * 128 + k] = h2d;
            *(unsigned short*)&W2t[(140 + hd) * 128 + k] = f2bf(vd2 - bfbits2f(h2d));
        }
    }
}

__global__ __launch_bounds__(256) void bucket_scatter(const int* __restrict__ dst,
                                                      const int* __restrict__ src,
                                                      int* __restrict__ gcursor,
                                                      int* __restrict__ pairs,
                                                      int E, int nbuck) {
    __shared__ int hist[256], lcur[256];
    int t = threadIdx.x;
    for (int i = t; i < nbuck; i += 256) hist[i] = 0;
    __syncthreads();
    int base = blockIdx.x * 2048;
    int dreg[8];
    #pragma unroll
    for (int k = 0; k < 8; ++k) {
        int e = base + k * 256 + t;
        int d = (e < E) ? dst[e] : -1;
        dreg[k] = d;
        if (d >= 0) atomicAdd(&hist[d >> 8], 1);
    }
    __syncthreads();
    for (int i = t; i < nbuck; i += 256) {
        int c = hist[i];
        lcur[i] = c ? atomicAdd(&gcursor[i], c) : 0;   // reserve contiguous run
    }
    __syncthreads();
    #pragma unroll
    for (int k = 0; k < 8; ++k) {
        int e = base + k * 256 + t;
        if (e < E) {
            int d = dreg[k];
            int p = atomicAdd(&lcur[d >> 8], 1);
            pairs[p] = ((d & 255) << 17) | src[e];
        }
    }
}

__global__ __launch_bounds__(256) void bucket_fill(const int* __restrict__ pairs,
                                                   const int* __restrict__ gcursor,
                                                   int2* __restrict__ rowdeg,
                                                   int* __restrict__ colsrc, int n) {
    __shared__ int deg[256], excl[256], cur[256];
    int b = blockIdx.x, t = threadIdx.x;
    int e0 = b * BCAP, e1 = gcursor[b];
    int d0 = b << 8;
    deg[t] = 0;
    __syncthreads();
    for (int j = e0 + t; j < e1; j += 256)
        atomicAdd(&deg[pairs[j] >> 17], 1);
    __syncthreads();
    int v = deg[t];
    excl[t] = v;
    __syncthreads();
    for (int off = 1; off < 256; off <<= 1) {
        int u = (t >= off) ? excl[t - off] : 0;
        __syncthreads();
        excl[t] += u;
        __syncthreads();
    }
    int base = e0 + excl[t] - v;                   // exclusive within bucket
    if (d0 + t < n) rowdeg[d0 + t] = make_int2(base, v);
    cur[t] = base;
    __syncthreads();
    for (int j = e0 + t; j < e1; j += 256) {
        int w = pairs[j];
        int p = atomicAdd(&cur[w >> 17], 1);
        colsrc[p] = w & 0x1FFFF;
    }
}

// ---------------- GAT GEMM via MFMA: [h | a_s | a_d] = X @ Wt(144 cols) ----------
template <typename T>
__global__ __launch_bounds__(256) void gemm_att_mfma(
    const T* __restrict__ X, const __hip_bfloat16* __restrict__ Wt,
    __hip_bfloat16* __restrict__ h, float* __restrict__ a_s, float* __restrict__ a_d, int n)
{
    __shared__ __align__(16) __hip_bfloat16 sWt[144 * 136];   // [col][k], +8 pad
    int t = threadIdx.x;
    for (int i = t; i < 144 * 16; i += 256) {
        int row = i >> 4, ch = i & 15;
        *(int4*)&sWt[row * 136 + ch * 8] = *(const int4*)&Wt[row * 128 + ch * 8];
    }
    __syncthreads();
    int wave = t >> 6, lane = t & 63, quad = lane >> 4, l16 = lane & 15;
    int rowbase = (blockIdx.x * 4 + wave) * 16;
    if (rowbase >= n) return;

    v8bf z;
    #pragma unroll
    for (int i = 0; i < 8; ++i) z[i] = (__bf16)0.f;
    int arow = rowbase + l16;
    bool ok = arow < n;
    v8bf af[4];
    if constexpr (std::is_same<T, float>::value) {
        const float* xf = X + (size_t)(ok ? arow : 0) * 128;
        #pragma unroll
        for (int ks = 0; ks < 4; ++ks) {
            if (ok) {
                float4 u = *(const float4*)&xf[ks * 32 + quad * 8];
                float4 v = *(const float4*)&xf[ks * 32 + quad * 8 + 4];
                v8bf a;
                unsigned short r;
                r = f2bf(u.x); a[0] = *(__bf16*)&r;
                r = f2bf(u.y); a[1] = *(__bf16*)&r;
                r = f2bf(u.z); a[2] = *(__bf16*)&r;
                r = f2bf(u.w); a[3] = *(__bf16*)&r;
                r = f2bf(v.x); a[4] = *(__bf16*)&r;
                r = f2bf(v.y); a[5] = *(__bf16*)&r;
                r = f2bf(v.z); a[6] = *(__bf16*)&r;
                r = f2bf(v.w); a[7] = *(__bf16*)&r;
                af[ks] = a;
            } else af[ks] = z;
        }
    } else {
        const v8bf* px = (const v8bf*)(X + (size_t)(ok ? arow : 0) * 128);
        #pragma unroll
        for (int ks = 0; ks < 4; ++ks) af[ks] = ok ? px[ks * 4 + quad] : z;
    }

    v4f acc[9];
    #pragma unroll
    for (int ct = 0; ct < 9; ++ct) acc[ct] = (v4f){0.f, 0.f, 0.f, 0.f};
    #pragma unroll
    for (int ct = 0; ct < 9; ++ct) {
        #pragma unroll
        for (int ks = 0; ks < 4; ++ks) {
            v8bf b = *(const v8bf*)&sWt[(ct * 16 + l16) * 136 + ks * 32 + quad * 8];
            acc[ct] = __builtin_amdgcn_mfma_f32_16x16x32_bf16(af[ks], b, acc[ct], 0, 0, 0);
        }
    }

    // h store (tiles 0..7): C layout col=l16, row=quad*4+reg
    #pragma unroll
    for (int reg = 0; reg < 4; ++reg) {
        int r = rowbase + quad * 4 + reg;
        if (r < n) {
            #pragma unroll
            for (int ct = 0; ct < 8; ++ct)
                *(unsigned short*)&h[(size_t)r * 128 + ct * 16 + l16] = f2bf(acc[ct][reg]);
        }
    }
    // tile 8 = attention dots: cols l16: 0-3 s_hi, 4-7 s_lo, 8-11 d_hi, 12-15 d_lo
    #pragma unroll
    for (int reg = 0; reg < 4; ++reg) {
        float v = acc[8][reg] + __shfl_xor(acc[8][reg], 4);   // hi + lo
        int r = rowbase + quad * 4 + reg;
        if (r < n) {
            if (l16 < 4)                    a_s[r * 4 + l16] = v;
            else if (l16 >= 8 && l16 < 12)  a_d[r * 4 + (l16 - 8)] = v;
        }
    }
}

// ---------------- GAT: wave-per-dst aggregation (R9 28-VGPR inner loop) -----------
__global__ __launch_bounds__(256) void gat_aggr(
    const __hip_bfloat16* __restrict__ h, const float* __restrict__ a_s,
    const float* __restrict__ a_d,
    const int2* __restrict__ rowdeg, const int* __restrict__ colsrc,
    const float* __restrict__ bias, __hip_bfloat16* __restrict__ out, int n)
{
    __shared__ float s_w[4][64 * 4];
    int t = threadIdx.x;
    int wave = t >> 6, lane = t & 63;
    int d = blockIdx.x * 4 + wave;
    if (d >= n) d = n - 1;                         // duplicate work, benign
    int2 rd = rowdeg[d];
    int beg = rd.x, cnt = rd.y;
    float4 ad4 = *(const float4*)&a_d[d * 4];
    float4 asd = *(const float4*)&a_s[d * 4];
    float es0 = lrelu(asd.x + ad4.x), es1 = lrelu(asd.y + ad4.y);
    float es2 = lrelu(asd.z + ad4.z), es3 = lrelu(asd.w + ad4.w);
    float z0 = 0.f, z1 = 0.f, z2 = 0.f, z3 = 0.f;   // per-lane partials

    int l16 = lane & 15, egrp = lane >> 4;
    unsigned ch2 = (unsigned)(l16 * 16);            // byte offset of channels
    int head = l16 >> 2;
    v2f a2[4];
    #pragma unroll
    for (int i = 0; i < 4; ++i) a2[i] = (v2f){0.f, 0.f};

    for (int j0 = 0; j0 < cnt; j0 += 64) {
        int ne = min(64, cnt - j0);
        float w0 = 0.f, w1 = 0.f, w2 = 0.f, w3 = 0.f;
        int s = 0;                                  // row 0 is a valid address
        if (lane < ne) {
            s = colsrc[beg + j0 + lane];
            float4 sv = *(const float4*)&a_s[s * 4];
            w0 = __expf(lrelu(sv.x + ad4.x));
            w1 = __expf(lrelu(sv.y + ad4.y));
            w2 = __expf(lrelu(sv.z + ad4.z));
            w3 = __expf(lrelu(sv.w + ad4.w));
        }
        z0 += w0; z1 += w1; z2 += w2; z3 += w3;
        float4 wv = {w0, w1, w2, w3};               // zeros for pad lanes
        *(float4*)&s_w[wave][lane * 4] = wv;
        __asm volatile("s_waitcnt lgkmcnt(0)" ::: "memory");  // wave-sync LDS
        // branchless: s_w==0 and s==0 for pad lanes -> contributes exactly 0.
        int kmax = (ne + 3) >> 2;                   // uniform trip count
        #pragma unroll 2
        for (int k = 0; k < kmax; ++k) {
            int j = egrp + 4 * k;
            int ss = __shfl(s, j);
            float wj = s_w[wave][j * 4 + head];
            v2f w2v = {wj, wj};
            unsigned off = ((unsigned)ss << 8) + ch2;   // saddr-friendly 32-bit
            int4 u = *(const int4*)((const char*)h + off);
            a2[0] += w2v * up2(u.x);
            a2[1] += w2v * up2(u.y);
            a2[2] += w2v * up2(u.z);
            a2[3] += w2v * up2(u.w);
        }
    }
    float acc[8] = {a2[0].x, a2[0].y, a2[1].x, a2[1].y,
                    a2[2].x, a2[2].y, a2[3].x, a2[3].y};
    #pragma unroll
    for (int off = 1; off < 64; off <<= 1) {
        z0 += __shfl_xor(z0, off);
        z1 += __shfl_xor(z1, off);
        z2 += __shfl_xor(z2, off);
        z3 += __shfl_xor(z3, off);
    }
    #pragma unroll
    for (int off = 16; off < 64; off <<= 1)
        #pragma unroll
        for (int i = 0; i < 8; ++i) acc[i] += __shfl_xor(acc[i], off);

    if (egrp == 0) {                                // lanes 0..15 write 16B each
        int ch = l16 * 8;
        float zh = (head < 2) ? (head == 0 ? z0 : z1) : (head == 2 ? z2 : z3);
        float eh = (head < 2) ? (head == 0 ? es0 : es1) : (head == 2 ? es2 : es3);
        float ws = __expf(eh);                      // self-loop weight
        float inv = 1.f / (zh + ws + 1e-16f);
        int4 hu = *(const int4*)&h[(size_t)d * 128 + ch];
        float hs[8] = {bflo(hu.x), bfhi(hu.x), bflo(hu.y), bfhi(hu.y),
                       bflo(hu.z), bfhi(hu.z), bflo(hu.w), bfhi(hu.w)};
        float4 b0 = *(const float4*)&bias[ch];
        float4 b1 = *(const float4*)&bias[ch + 4];
        float o[8];
        o[0] = fmaxf((acc[0] + ws * hs[0]) * inv + b0.x, 0.f);
        o[1] = fmaxf((acc[1] + ws * hs[1]) * inv + b0.y, 0.f);
        o[2] = fmaxf((acc[2] + ws * hs[2]) * inv + b0.z, 0.f);
        o[3] = fmaxf((acc[3] + ws * hs[3]) * inv + b0.w, 0.f);
        o[4] = fmaxf((acc[4] + ws * hs[4]) * inv + b1.x, 0.f);
        o[5] = fmaxf((acc[5] + ws * hs[5]) * inv + b1.y, 0.f);
        o[6] = fmaxf((acc[6] + ws * hs[6]) * inv + b1.z, 0.f);
        o[7] = fmaxf((acc[7] + ws * hs[7]) * inv + b1.w, 0.f);
        int4 ou;
        ou.x = packbf2(o[0], o[1]); ou.y = packbf2(o[2], o[3]);
        ou.z = packbf2(o[4], o[5]); ou.w = packbf2(o[6], o[7]);
        *(int4*)&out[(size_t)d * 128 + ch] = ou;
    }
}

// ---------------- GraphConv linear: y = x@Wr (bf16), root = x@Wl + b (fp32) -------
__global__ __launch_bounds__(256) void graphconv_lin(
    const __hip_bfloat16* __restrict__ Xb,
    const __hip_bfloat16* __restrict__ Wrt, const __hip_bfloat16* __restrict__ Wlt,
    const float* __restrict__ bias, __hip_bfloat16* __restrict__ y,
    float* __restrict__ root, int n)
{
    __shared__ __align__(16) __hip_bfloat16 sWr[32 * 136], sWl[32 * 136];
    int t = threadIdx.x;
    for (int i = t; i < 32 * 16; i += 256) {
        int row = i >> 4, ch = i & 15;
        *(int4*)&sWr[row * 136 + ch * 8] = *(const int4*)&Wrt[row * 128 + ch * 8];
        *(int4*)&sWl[row * 136 + ch * 8] = *(const int4*)&Wlt[row * 128 + ch * 8];
    }
    __syncthreads();
    int wave = t >> 6, lane = t & 63, quad = lane >> 4, l16 = lane & 15;
    int rowbase = (blockIdx.x * 4 + wave) * 16;
    if (rowbase >= n) return;

    v8bf z;
    #pragma unroll
    for (int i = 0; i < 8; ++i) z[i] = (__bf16)0.f;
    int arow = rowbase + l16;
    bool ok = arow < n;
    const v8bf* px = (const v8bf*)(Xb + (size_t)(ok ? arow : 0) * 128);
    v8bf fx[4];
    #pragma unroll
    for (int ks = 0; ks < 4; ++ks) fx[ks] = ok ? px[ks * 4 + quad] : z;

    v4f accR[2], accL[2];
    #pragma unroll
    for (int ct = 0; ct < 2; ++ct) {
        accR[ct] = (v4f){0.f, 0.f, 0.f, 0.f};
        accL[ct] = (v4f){0.f, 0.f, 0.f, 0.f};
        #pragma unroll
        for (int ks = 0; ks < 4; ++ks) {
            v8bf br = *(const v8bf*)&sWr[(ct * 16 + l16) * 136 + ks * 32 + quad * 8];
            accR[ct] = __builtin_amdgcn_mfma_f32_16x16x32_bf16(fx[ks], br, accR[ct], 0, 0, 0);
            v8bf bl = *(const v8bf*)&sWl[(ct * 16 + l16) * 136 + ks * 32 + quad * 8];
            accL[ct] = __builtin_amdgcn_mfma_f32_16x16x32_bf16(fx[ks], bl, accL[ct], 0, 0, 0);
        }
    }
    #pragma unroll
    for (int ct = 0; ct < 2; ++ct) {
        float bcol = bias[ct * 16 + l16];
        #pragma unroll
        for (int reg = 0; reg < 4; ++reg) {
            int r = rowbase + quad * 4 + reg;
            if (r < n) {
                *(unsigned short*)&y[(size_t)r * 32 + ct * 16 + l16] = f2bf(accR[ct][reg]);
                root[(size_t)r * 32 + ct * 16 + l16] = accL[ct][reg] + bcol;
            }
        }
    }
}

// ---------------- GraphConv aggr: x3 = relu(sum_{src} y[src] + root), 32 ch -------
__global__ __launch_bounds__(256) void graphconv_aggr(
    const __hip_bfloat16* __restrict__ y, const float* __restrict__ root,
    const int2* __restrict__ rowdeg, const int* __restrict__ colsrc,
    __hip_bfloat16* __restrict__ x3, int n)
{
    int t = threadIdx.x;
    int wave = t >> 6, lane = t & 63;
    int d = blockIdx.x * 4 + wave;
    if (d >= n) d = n - 1;
    int2 rd = rowdeg[d];
    int beg = rd.x, cnt = rd.y;
    int l4 = lane & 3, egrp = lane >> 2;      // 16 edges concurrent, 4 lanes/row
    unsigned ch2 = (unsigned)(l4 * 16);
    v2f a2[4];
    #pragma unroll
    for (int i = 0; i < 4; ++i) a2[i] = (v2f){0.f, 0.f};
    for (int j0 = 0; j0 < cnt; j0 += 64) {
        int ne = min(64, cnt - j0);
        int s = (lane < ne) ? colsrc[beg + j0 + lane] : 0;
        int kmax = (ne + 15) >> 4;                  // uniform trip count
        #pragma unroll 2
        for (int k = 0; k < kmax; ++k) {
            int j = egrp + 16 * k;                  // <= 63 always
            int ss = __shfl(s, j);
            float m = (j < ne) ? 1.f : 0.f;         // branchless mask
            v2f m2 = {m, m};
            unsigned off = ((unsigned)ss << 6) + ch2;
            int4 u = *(const int4*)((const char*)y + off);
            a2[0] += m2 * up2(u.x);
            a2[1] += m2 * up2(u.y);
            a2[2] += m2 * up2(u.z);
            a2[3] += m2 * up2(u.w);
        }
    }
    float acc[8] = {a2[0].x, a2[0].y, a2[1].x, a2[1].y,
                    a2[2].x, a2[2].y, a2[3].x, a2[3].y};
    #pragma unroll
    for (int off = 4; off < 64; off <<= 1)
        #pragma unroll
        for (int i = 0; i < 8; ++i) acc[i] += __shfl_xor(acc[i], off);
    if (egrp == 0) {                           // lanes 0..3 write 16B each
        int ch = l4 * 8;
        float4 r0 = *(const float4*)&root[(size_t)d * 32 + ch];
        float4 r1 = *(const float4*)&root[(size_t)d * 32 + ch + 4];
        float o[8];
        o[0] = fmaxf(acc[0] + r0.x, 0.f); o[1] = fmaxf(acc[1] + r0.y, 0.f);
        o[2] = fmaxf(acc[2] + r0.z, 0.f); o[3] = fmaxf(acc[3] + r0.w, 0.f);
        o[4] = fmaxf(acc[4] + r1.x, 0.f); o[5] = fmaxf(acc[5] + r1.y, 0.f);
        o[6] = fmaxf(acc[6] + r1.z, 0.f); o[7] = fmaxf(acc[7] + r1.w, 0.f);
        int4 ou;
        ou.x = packbf2(o[0], o[1]); ou.y = packbf2(o[2], o[3]);
        ou.z = packbf2(o[4], o[5]); ou.w = packbf2(o[6], o[7]);
        *(int4*)&x3[(size_t)d * 32 + ch] = ou;
    }
}

// ---------------- SAGE fused: mean gather + out = relu(mean@Wl+bl + x3@Wr) --------
__global__ __launch_bounds__(256) void sage_fused(
    const __hip_bfloat16* __restrict__ x3, const int2* __restrict__ rowdeg,
    const int* __restrict__ colsrc,
    const float* __restrict__ W4l, const float* __restrict__ b4l,
    const float* __restrict__ W4r, float* __restrict__ out, int n)
{
    __shared__ __align__(16) float sWl[32 * 32], sWr[32 * 32];
    __shared__ float s_mean[4][32], s_x3[4][32];
    int t = threadIdx.x;
    for (int i = t; i < 1024; i += 256) { sWl[i] = W4l[i]; sWr[i] = W4r[i]; }
    __syncthreads();

    int wave = t >> 6, lane = t & 63;
    int d = blockIdx.x * 4 + wave;
    if (d >= n) d = n - 1;
    int2 rd = rowdeg[d];
    int beg = rd.x, cnt = rd.y;
    int l4 = lane & 3, egrp = lane >> 2;
    unsigned ch2 = (unsigned)(l4 * 16);
    v2f a2[4];
    #pragma unroll
    for (int i = 0; i < 4; ++i) a2[i] = (v2f){0.f, 0.f};
    for (int j0 = 0; j0 < cnt; j0 += 64) {
        int ne = min(64, cnt - j0);
        int s = (lane < ne) ? colsrc[beg + j0 + lane] : 0;
        int kmax = (ne + 15) >> 4;
        #pragma unroll 2
        for (int k = 0; k < kmax; ++k) {
            int j = egrp + 16 * k;
            int ss = __shfl(s, j);
            float m = (j < ne) ? 1.f : 0.f;
            v2f m2 = {m, m};
            unsigned off = ((unsigned)ss << 6) + ch2;
            int4 u = *(const int4*)((const char*)x3 + off);
            a2[0] += m2 * up2(u.x);
            a2[1] += m2 * up2(u.y);
            a2[2] += m2 * up2(u.z);
            a2[3] += m2 * up2(u.w);
        }
    }
    float acc[8] = {a2[0].x, a2[0].y, a2[1].x, a2[1].y,
                    a2[2].x, a2[2].y, a2[3].x, a2[3].y};
    #pragma unroll
    for (int off = 4; off < 64; off <<= 1)
        #pragma unroll
        for (int i = 0; i < 8; ++i) acc[i] += __shfl_xor(acc[i], off);
    if (egrp == 0) {                           // lanes 0..3: mean + self row to LDS
        int ch = l4 * 8;
        float invd = 1.f / fmaxf((float)cnt, 1.f);
        int4 xr = *(const int4*)&x3[(size_t)d * 32 + ch];
        #pragma unroll
        for (int i = 0; i < 8; ++i) s_mean[wave][ch + i] = acc[i] * invd;
        s_x3[wave][ch + 0] = bflo(xr.x); s_x3[wave][ch + 1] = bfhi(xr.x);
        s_x3[wave][ch + 2] = bflo(xr.y); s_x3[wave][ch + 3] = bfhi(xr.y);
        s_x3[wave][ch + 4] = bflo(xr.z); s_x3[wave][ch + 5] = bfhi(xr.z);
        s_x3[wave][ch + 6] = bflo(xr.w); s_x3[wave][ch + 7] = bfhi(xr.w);
    }
    __asm volatile("s_waitcnt lgkmcnt(0)" ::: "memory");  // wave-sync LDS
    // matvec: c = lane&31, half = lane>>5 covers k-range half*16..+16
    int c = lane & 31, half = lane >> 5;
    const float* sm = &s_mean[wave][half * 16];
    const float* sx = &s_x3[wave][half * 16];
    float acc2 = 0.f;
    #pragma unroll
    for (int k = 0; k < 16; ++k) {
        int kk = half * 16 + k;
        acc2 += sm[k] * sWl[kk * 32 + c] + sx[k] * sWr[kk * 32 + c];
    }
    acc2 += __shfl_xor(acc2, 32);
    if (half == 0 && d < n)
        out[(size_t)d * 32 + c] = fmaxf(acc2 + b4l[c], 0.f);
}

// ---------------- global mean pool (batch sorted) ----------------
__device__ __forceinline__ int lower_bound_i(const int* a, int n, int key) {
    int lo = 0, hi = n;
    while (lo < hi) { int mid = (lo + hi) >> 1; if (a[mid] < key) lo = mid + 1; else hi = mid; }
    return lo;
}

__global__ __launch_bounds__(256) void pool_kernel(
    const float* __restrict__ x, const int* __restrict__ batch,
    float* __restrict__ gpool, int n)
{
    int g = blockIdx.x;
    int lo = lower_bound_i(batch, n, g);
    int hi = lower_bound_i(batch, n, g + 1);
    int t = threadIdx.x;
    int c = t & 31, rr = t >> 5;
    float acc = 0.f;
    for (int i = lo + rr; i < hi; i += 8) acc += x[i * 32 + c];
    __shared__ float sred[256];
    sred[t] = acc;
    __syncthreads();
    if (t < 128) sred[t] += sred[t + 128];
    __syncthreads();
    if (t < 64) sred[t] += sred[t + 64];
    __syncthreads();
    if (t < 32) {
        float v = sred[t] + sred[t + 32];
        gpool[g * 32 + t] = v / fmaxf((float)(hi - lo), 1.f);
    }
}

// ---------------- MLP head ----------------
__global__ __launch_bounds__(256) void head_kernel(
    const float* __restrict__ gpool, const float* __restrict__ Wf1, const float* __restrict__ bf1,
    const float* __restrict__ Wf2, const float* __restrict__ bf2, float* __restrict__ out)
{
    __shared__ float sg[64 * 32], st[64 * 32];
    __shared__ float sW1[32 * 32], sW2[32 * 10];
    int t = threadIdx.x;
    for (int i = t; i < 2048; i += 256) sg[i] = gpool[i];
    for (int i = t; i < 1024; i += 256) sW1[i] = Wf1[i];
    for (int i = t; i < 320; i += 256) sW2[i] = Wf2[i];
    __syncthreads();
    for (int i = t; i < 2048; i += 256) {
        int g = i >> 5, c = i & 31;
        float acc = bf1[c];
        #pragma unroll
        for (int k = 0; k < 32; ++k) acc += sg[g * 32 + k] * sW1[k * 32 + c];
        st[i] = fmaxf(acc, 0.f);
    }
    __syncthreads();
    for (int i = t; i < 640; i += 256) {
        int g = i / 10, o = i - g * 10;
        float acc = bf2[o];
        #pragma unroll
        for (int k = 0; k < 32; ++k) acc += st[g * 32 + k] * sW2[k * 10 + o];
        out[i] = acc;
    }
}

extern "C" void kernel_launch(void* const* d_in, const int* in_sizes, int n_in,
                              void* d_out, int out_size, void* d_ws, size_t ws_size,
                              hipStream_t stream) {
    const float* x    = (const float*)d_in[0];
    const int*   ei   = (const int*)d_in[1];
    const int*   batch= (const int*)d_in[2];
    const float* W1   = (const float*)d_in[3];
    const float* as1  = (const float*)d_in[4];
    const float* ad1  = (const float*)d_in[5];
    const float* b1   = (const float*)d_in[6];
    const float* W2   = (const float*)d_in[7];
    const float* as2  = (const float*)d_in[8];
    const float* ad2  = (const float*)d_in[9];
    const float* b2   = (const float*)d_in[10];
    const float* W3r  = (const float*)d_in[11];
    const float* W3l  = (const float*)d_in[12];
    const float* b3   = (const float*)d_in[13];
    const float* W4l  = (const float*)d_in[14];
    const float* b4l  = (const float*)d_in[15];
    const float* W4r  = (const float*)d_in[16];
    const float* Wf1  = (const float*)d_in[17];
    const float* bf1  = (const float*)d_in[18];
    const float* Wf2  = (const float*)d_in[19];
    const float* bf2  = (const float*)d_in[20];

    const int N = in_sizes[0] / 128;
    const int E = in_sizes[1] / 2;
    const int* src = ei;
    const int* dst = ei + E;

    char* p = (char*)d_ws;
    auto alloc = [&](size_t bytes) -> void* {
        void* r = (void*)p;
        p += (bytes + 255) & ~(size_t)255;
        return r;
    };
    const int nbuck = (N + 255) >> 8;     // 196 for N=50000 (requires N<=65536)

    __hip_bfloat16* buf1 = (__hip_bfloat16*)alloc((size_t)N * 128 * 2);  // x2 / X4
    __hip_bfloat16* buf2 = (__hip_bfloat16*)alloc((size_t)N * 128 * 2);  // x1 / x3
    __hip_bfloat16* buf3 = (__hip_bfloat16*)alloc((size_t)N * 128 * 2);  // pairs / h1,h2 / y+root
    float* aS     = (float*)alloc((size_t)N * 4 * 4);
    float* aD     = (float*)alloc((size_t)N * 4 * 4);
    int2*  rowdeg = (int2*)alloc((size_t)N * 8);
    int*   colsrc = (int*)alloc((size_t)nbuck * BCAP * 4);
    int*   gcursor= (int*)alloc(256 * 4);
    __hip_bfloat16* W1t  = (__hip_bfloat16*)alloc(144 * 128 * 2);
    __hip_bfloat16* W2t  = (__hip_bfloat16*)alloc(144 * 128 * 2);
    __hip_bfloat16* W3rt = (__hip_bfloat16*)alloc(32 * 128 * 2);
    __hip_bfloat16* W3lt = (__hip_bfloat16*)alloc(32 * 128 * 2);
    float* gpool  = (float*)alloc(64 * 32 * 4);

    // aliased views
    __hip_bfloat16* X3b  = buf2;                                        // N*32 bf16
    float*          X4   = (float*)buf1;                                // N*32 fp32
    __hip_bfloat16* Y32  = buf3;                                        // N*32 bf16
    float*          ROOT = (float*)((char*)buf3 + (((size_t)N * 32 * 2 + 255) & ~(size_t)255));
    int*            pairs = (int*)buf3;   // nbuck*BCAP*4 B <= 4.8 MB, consumed before h

    // ---- CSR build (fixed-capacity buckets) + weight prep: 3 dispatches ----
    prep_kernel<<<65, 256, 0, stream>>>(gcursor, W1, W2, W3r, W3l,
                                        as1, ad1, as2, ad2, W1t, W2t, W3rt, W3lt);
    bucket_scatter<<<(E + 2047) / 2048, 256, 0, stream>>>(dst, src, gcursor, pairs, E, nbuck);
    bucket_fill<<<nbuck, 256, 0, stream>>>(pairs, gcursor, rowdeg, colsrc, N);

    const int gmm = (N + 63) / 64;
    const int gag = (N + 3) / 4;
    // GAT layer 1 (reads fp32 x directly)
    gemm_att_mfma<float><<<gmm, 256, 0, stream>>>(x, W1t, buf3, aS, aD, N);
    gat_aggr<<<gag, 256, 0, stream>>>(buf3, aS, aD, rowdeg, colsrc, b1, buf2, N);
    // GAT layer 2
    gemm_att_mfma<__hip_bfloat16><<<gmm, 256, 0, stream>>>(buf2, W2t, buf3, aS, aD, N);
    gat_aggr<<<gag, 256, 0, stream>>>(buf3, aS, aD, rowdeg, colsrc, b2, buf1, N);
    // GraphConv (project first, then 64B-row gather)
    graphconv_lin<<<gmm, 256, 0, stream>>>(buf1, W3rt, W3lt, b3, Y32, ROOT, N);
    graphconv_aggr<<<gag, 256, 0, stream>>>(Y32, ROOT, rowdeg, colsrc, X3b, N);
    // SAGE (mean gather + GEMM fused; MEAN never materialized)
    sage_fused<<<gag, 256, 0, stream>>>(X3b, rowdeg, colsrc, W4l, b4l, W4r, X4, N);
    // pool + head
    pool_kernel<<<64, 256, 0, stream>>>(X4, batch, gpool, N);
    head_kernel<<<1, 256, 0, stream>>>(gpool, Wf1, bf1, Wf2, bf2, (float*)d_out);
}